// Round 6
// baseline (220.432 us; speedup 1.0000x reference)
//
#include <hip/hip_runtime.h>

#define TPB_PACK  256
#define P1_BLOCKS 768
#define P1_TPB    512
#define REP       2                      // scnt replicas (per wave parity)
#define PRODUCERS (P1_BLOCKS * REP)
#define BUCKET_BITS 10
#define BS (1 << BUCKET_BITS)            // atoms per bucket
#define P2_TPB    256
#define P2_S      8                      // sub-blocks per bucket in phase 2
#define PPS       (PRODUCERS / P2_S)     // producers per sub-block (192)
#define TPB_RED   256
#define CMAX      48
#define NB_MAX    256

// ---- pack atom types into 2 bits each: word w covers atoms [16w, 16w+15] ----
__global__ __launch_bounds__(TPB_PACK) void zbl_pack(
    const int* __restrict__ types, unsigned int* __restrict__ packed,
    int natoms, int nwords)
{
    int w = blockIdx.x * TPB_PACK + threadIdx.x;
    if (w >= nwords) return;
    int base = w << 4;
    unsigned int word = 0;
    #pragma unroll
    for (int j = 0; j < 16; ++j) {
        int i = base + j;
        unsigned int t = (i < natoms) ? (unsigned int)types[i] : 0u;
        word |= (t & 3u) << (2 * j);
    }
    packed[w] = word;
}

// ------- Phase 1: LDS type table, compute e, bin 4 B records -------
// record = (f32 e, low 10 mantissa bits replaced) | (atom & 1023)
__global__ __launch_bounds__(P1_TPB) void zbl_bin(
    const float* __restrict__ rij,
    const float* __restrict__ rcov,
    const float* __restrict__ znum,
    const int*  __restrict__ fa,
    const int*  __restrict__ sa,
    const unsigned int* __restrict__ packed,
    unsigned int* __restrict__ regions,  // [PRODUCERS][NB][C]
    int*   __restrict__ counts,          // [NB][PRODUCERS] (transposed)
    float* __restrict__ fallback,        // natoms floats, pre-zeroed (= d_out if C==0)
    int E, int nquad, int natoms, int nwords, int NB, int C, int chunkQ)
{
    extern __shared__ unsigned int s_packed[];   // nwords words (~50 KB)
    __shared__ float tab[9][16];
    __shared__ int scnt[REP * NB_MAX];

    for (int w = threadIdx.x; w < nwords; w += P1_TPB)
        s_packed[w] = packed[w];                 // coalesced, L2-resident
    for (int t = threadIdx.x; t < REP * NB; t += P1_TPB) scnt[t] = 0;

    if (threadIdx.x < 16) {
        const float cc[4] = {0.02817f, 0.28022f, 0.50986f, 0.18175f};
        const float dd[4] = {0.20162f, 0.4029f, 0.94229f, 3.1998f};
        const float COUL = 14.399645478425668f;
        int t = threadIdx.x;
        int ti = t >> 2, tj = t & 3;
        float zi = znum[ti], zj = znum[tj];
        float rc = rcov[ti] + rcov[tj];
        float a = 0.4685f / (powf(zi, 0.23f) + powf(zj, 0.23f));
        float inva = 1.0f / a;
        float factor = COUL * zi * zj;
        float da[4], ee[4];
        float phi = 0.0f, dphi = 0.0f, d2phi = 0.0f;
        #pragma unroll
        for (int k = 0; k < 4; ++k) {
            da[k] = dd[k] * inva;
            ee[k] = expf(-rc * da[k]);
            phi   += cc[k] * ee[k];
            dphi  -= cc[k] * da[k] * ee[k];
            d2phi += cc[k] * da[k] * da[k] * ee[k];
        }
        float invrc = 1.0f / rc;
        float ec   = factor * invrc * phi;
        float dec  = factor * invrc * (-phi * invrc + dphi);
        float d2ec = factor * invrc * (d2phi - 2.0f * invrc * dphi + 2.0f * phi * invrc * invrc);
        float A = (-3.0f * dec + rc * d2ec) * invrc * invrc;
        float B = (2.0f * dec - rc * d2ec) * invrc * invrc * invrc;
        float Cc = -ec + 0.5f * rc * dec - rc * rc * d2ec * (1.0f / 12.0f);
        const float L2E = 1.4426950408889634f;
        tab[0][t] = 0.5f * factor;      // folds final e/2
        tab[1][t] = rc;
        tab[2][t] = -da[0] * L2E;       // c*exp(-r*da) = exp2(r*slope + log2 c)
        tab[3][t] = -da[1] * L2E;
        tab[4][t] = -da[2] * L2E;
        tab[5][t] = -da[3] * L2E;
        tab[6][t] = A * (1.0f / 6.0f);
        tab[7][t] = B * 0.125f;
        tab[8][t] = Cc * 0.5f;
    }
    __syncthreads();

    const float lc0 = -5.1497481f;   // log2(0.02817)
    const float lc1 = -1.8353434f;   // log2(0.28022)
    const float lc2 = -0.9718340f;   // log2(0.50986)
    const float lc3 = -2.4600449f;   // log2(0.18175)

    const float4* rij4 = (const float4*)rij;
    const int4*   fa4  = (const int4*)fa;
    const int4*   sa4  = (const int4*)sa;

    int rep = (threadIdx.x >> 6) & (REP - 1);    // wave-parity counter replica
    int vp  = blockIdx.x * REP + rep;

    int q0 = blockIdx.x * chunkQ;
    int q1 = q0 + chunkQ; if (q1 > nquad) q1 = nquad;

    for (int q = q0 + threadIdx.x; q < q1; q += P1_TPB) {
        float4 rv = rij4[q];
        int4   iv = fa4[q];
        int4   jv = sa4[q];
        float ra[4] = {rv.x, rv.y, rv.z, rv.w};
        int   ia[4] = {iv.x, iv.y, iv.z, iv.w};
        int   ja[4] = {jv.x, jv.y, jv.z, jv.w};
        int   ta[4];
        #pragma unroll
        for (int k = 0; k < 4; ++k) {
            int i = ia[k], j = ja[k];
            unsigned int wi = s_packed[i >> 4], wj = s_packed[j >> 4];
            unsigned int ti = (wi >> ((i & 15) * 2)) & 3u;
            unsigned int tj = (wj >> ((j & 15) * 2)) & 3u;
            ta[k] = (int)((ti << 2) | tj);
        }
        #pragma unroll
        for (int k = 0; k < 4; ++k) {
            int t = ta[k];
            float r = ra[k];
            if (r <= tab[1][t]) {
                float p = __builtin_amdgcn_exp2f(__builtin_fmaf(r, tab[2][t], lc0))
                        + __builtin_amdgcn_exp2f(__builtin_fmaf(r, tab[3][t], lc1))
                        + __builtin_amdgcn_exp2f(__builtin_fmaf(r, tab[4][t], lc2))
                        + __builtin_amdgcn_exp2f(__builtin_fmaf(r, tab[5][t], lc3));
                float r3 = r * r * r;
                float poly = __builtin_fmaf(__builtin_fmaf(tab[7][t], r, tab[6][t]), r3, tab[8][t]);
                float e = __builtin_fmaf(tab[0][t] * p, __builtin_amdgcn_rcpf(r), poly);
                int atom = ia[k];
                int b = atom >> BUCKET_BITS;
                int slot = atomicAdd(&scnt[rep * NB + b], 1);   // LDS atomic
                if (slot < C) {
                    unsigned rec = ((__float_as_uint(e) + 0x200u) & 0xFFFFFC00u)
                                 | (unsigned)(atom & (BS - 1));
                    regions[((size_t)vp * NB + b) * (size_t)C + slot] = rec;
                } else {
                    unsafeAtomicAdd(&fallback[atom], e);        // rare overflow
                }
            }
        }
    }

    // tail (E % 4 != 0) handled by block 0
    if (blockIdx.x == 0) {
        for (int idx = nquad * 4 + threadIdx.x; idx < E; idx += P1_TPB) {
            int i = fa[idx], j = sa[idx];
            unsigned int wi = s_packed[i >> 4], wj = s_packed[j >> 4];
            int t = (int)((((wi >> ((i & 15) * 2)) & 3u) << 2) |
                           ((wj >> ((j & 15) * 2)) & 3u));
            float r = rij[idx];
            if (r <= tab[1][t]) {
                float p = __builtin_amdgcn_exp2f(__builtin_fmaf(r, tab[2][t], lc0))
                        + __builtin_amdgcn_exp2f(__builtin_fmaf(r, tab[3][t], lc1))
                        + __builtin_amdgcn_exp2f(__builtin_fmaf(r, tab[4][t], lc2))
                        + __builtin_amdgcn_exp2f(__builtin_fmaf(r, tab[5][t], lc3));
                float r3 = r * r * r;
                float poly = __builtin_fmaf(__builtin_fmaf(tab[7][t], r, tab[6][t]), r3, tab[8][t]);
                float e = __builtin_fmaf(tab[0][t] * p, __builtin_amdgcn_rcpf(r), poly);
                int b = i >> BUCKET_BITS;
                int slot = atomicAdd(&scnt[rep * NB + b], 1);
                if (slot < C) {
                    unsigned rec = ((__float_as_uint(e) + 0x200u) & 0xFFFFFC00u)
                                 | (unsigned)(i & (BS - 1));
                    regions[((size_t)vp * NB + b) * (size_t)C + slot] = rec;
                } else {
                    unsafeAtomicAdd(&fallback[i], e);
                }
            }
        }
    }

    __syncthreads();
    if (C > 0) {
        for (int t = threadIdx.x; t < REP * NB; t += P1_TPB) {
            int rr = t / NB, b = t - rr * NB;
            counts[(size_t)b * PRODUCERS + blockIdx.x * REP + rr] = min(scnt[t], C);
        }
    }
}

// ------- Phase 2: (bucket, sub-block) LDS aggregation -> partials (NO atomics) -------
__global__ __launch_bounds__(P2_TPB) void zbl_agg(
    const unsigned int* __restrict__ regions,
    const int*  __restrict__ counts,     // [NB][PRODUCERS]
    float* __restrict__ partials,        // [NB][P2_S][BS]
    int NB, int C)
{
    __shared__ float acc[BS];
    __shared__ int s_n[PPS];

    int b = blockIdx.x;                  // bucket
    int s = blockIdx.y;                  // sub-block
    for (int i = threadIdx.x; i < BS; i += P2_TPB) acc[i] = 0.0f;
    for (int pi = threadIdx.x; pi < PPS; pi += P2_TPB)
        s_n[pi] = counts[(size_t)b * PRODUCERS + pi * P2_S + s];
    __syncthreads();

    int wave = threadIdx.x >> 6;
    int lane = threadIdx.x & 63;
    for (int pi = wave; pi < PPS; pi += (P2_TPB >> 6)) {
        int n = s_n[pi];                             // wave-uniform
        int vp = pi * P2_S + s;
        size_t base = ((size_t)vp * NB + b) * (size_t)C;
        for (int t = lane; t < n; t += 64) {
            unsigned rec = regions[base + t];        // coalesced 4 B
            atomicAdd(&acc[rec & (BS - 1)],
                      __uint_as_float(rec & ~(unsigned)(BS - 1)));  // ds_add_f32
        }
    }
    __syncthreads();

    float* dst = partials + ((size_t)b * P2_S + s) * BS;
    for (int i = threadIdx.x; i < BS; i += P2_TPB)
        dst[i] = acc[i];                             // plain coalesced stores
}

// ------- Phase 3: reduce P2_S partials + fallback -> out -------
__global__ __launch_bounds__(TPB_RED) void zbl_red(
    const float* __restrict__ partials,
    const float* __restrict__ fallback,
    float* __restrict__ out,
    int natoms)
{
    int atom = blockIdx.x * TPB_RED + threadIdx.x;
    if (atom >= natoms) return;
    int b = atom >> BUCKET_BITS, i = atom & (BS - 1);
    float s = fallback[atom];
    const float* p = partials + (size_t)b * P2_S * BS + i;
    #pragma unroll
    for (int k = 0; k < P2_S; ++k) s += p[(size_t)k * BS];
    out[atom] = s;
}

extern "C" void kernel_launch(void* const* d_in, const int* in_sizes, int n_in,
                              void* d_out, int out_size, void* d_ws, size_t ws_size,
                              hipStream_t stream) {
    const float* rij  = (const float*)d_in[0];
    const float* rcov = (const float*)d_in[1];
    const float* znum = (const float*)d_in[2];
    const int*   fa   = (const int*)d_in[3];
    const int*   sa   = (const int*)d_in[4];
    const int*   types= (const int*)d_in[5];
    float* out = (float*)d_out;
    int E = in_sizes[0];
    int natoms = out_size;
    int nquad = E / 4;
    int nwords = (natoms + 15) / 16;
    int NB = (natoms + BS - 1) >> BUCKET_BITS;   // 196 for 200K atoms (<= NB_MAX)
    int chunkQ = (nquad + P1_BLOCKS - 1) / P1_BLOCKS;

    // ws layout: [packed][counts][fallback][partials][regions...]
    size_t packed_bytes = ((size_t)nwords * 4 + 255) & ~(size_t)255;
    size_t cnt_bytes    = ((size_t)NB * PRODUCERS * 4 + 255) & ~(size_t)255;
    size_t fb_bytes     = ((size_t)natoms * 4 + 255) & ~(size_t)255;
    size_t part_bytes   = ((size_t)NB * P2_S * BS * 4 + 255) & ~(size_t)255;
    unsigned int* packed = (unsigned int*)d_ws;
    int*   counts   = (int*)  ((char*)d_ws + packed_bytes);
    float* fallback = (float*)((char*)d_ws + packed_bytes + cnt_bytes);
    float* partials = (float*)((char*)d_ws + packed_bytes + cnt_bytes + fb_bytes);
    unsigned int* regions = (unsigned int*)((char*)d_ws + packed_bytes + cnt_bytes
                                            + fb_bytes + part_bytes);

    long long avail = (long long)ws_size
                    - (long long)(packed_bytes + cnt_bytes + fb_bytes + part_bytes);
    int C = 0;
    if (avail > 0) C = (int)(avail / ((long long)PRODUCERS * (long long)NB * 4));
    if (C > CMAX) C = CMAX;

    size_t smem = (size_t)nwords * sizeof(unsigned int);

    zbl_pack<<<(nwords + TPB_PACK - 1) / TPB_PACK, TPB_PACK, 0, stream>>>(
        types, packed, natoms, nwords);

    if (C >= 4) {
        hipMemsetAsync(fallback, 0, fb_bytes, stream);
        zbl_bin<<<P1_BLOCKS, P1_TPB, smem, stream>>>(
            rij, rcov, znum, fa, sa, packed, regions, counts, fallback,
            E, nquad, natoms, nwords, NB, C, chunkQ);
        dim3 g2(NB, P2_S);
        zbl_agg<<<g2, P2_TPB, 0, stream>>>(regions, counts, partials, NB, C);
        zbl_red<<<(natoms + TPB_RED - 1) / TPB_RED, TPB_RED, 0, stream>>>(
            partials, fallback, out, natoms);
    } else {
        // ws too small: pure-atomic path directly into out (correct, slow)
        hipMemsetAsync(d_out, 0, (size_t)natoms * 4, stream);
        zbl_bin<<<P1_BLOCKS, P1_TPB, smem, stream>>>(
            rij, rcov, znum, fa, sa, packed, regions, counts, out,
            E, nquad, natoms, nwords, NB, 0, chunkQ);
    }
}

// Round 7
// 209.554 us; speedup vs baseline: 1.0519x; 1.0519x over previous
//
#include <hip/hip_runtime.h>

#define TPB_PACK  256
#define P1_BLOCKS 512
#define P1_TPB    512
#define SB_BITS   14
#define SBS       (1 << SB_BITS)     // atoms per super-bucket (16384)
#define NS_MAX    16
#define P2_TPB    1024
#define R_SUB     40                 // phase-2 replicas per super-bucket
#define TPB_RED   256
#define CAP_MAX   896

// ---- pack atom types into 2 bits each: word w covers atoms [16w, 16w+15] ----
__global__ __launch_bounds__(TPB_PACK) void zbl_pack(
    const int* __restrict__ types, unsigned int* __restrict__ packed,
    int natoms, int nwords)
{
    int w = blockIdx.x * TPB_PACK + threadIdx.x;
    if (w >= nwords) return;
    int base = w << 4;
    unsigned int word = 0;
    #pragma unroll
    for (int j = 0; j < 16; ++j) {
        int i = base + j;
        unsigned int t = (i < natoms) ? (unsigned int)types[i] : 0u;
        word |= (t & 3u) << (2 * j);
    }
    packed[w] = word;
}

// ------- Phase 1: LDS type table; wave-aggregated binning into NS super-buckets -------
__global__ __launch_bounds__(P1_TPB) void zbl_bin(
    const float* __restrict__ rij,
    const float* __restrict__ rcov,
    const float* __restrict__ znum,
    const int*  __restrict__ fa,
    const int*  __restrict__ sa,
    const unsigned int* __restrict__ packed,
    int2*  __restrict__ regions,     // [P1_BLOCKS][NS][cap] records {e_bits, atom}
    int*   __restrict__ counts,      // [NS][P1_BLOCKS] (transposed)
    float* __restrict__ fallback,    // natoms floats, pre-zeroed (= d_out if cap==0)
    int E, int nquad, int natoms, int nwords, int NS, int cap, int chunkQ)
{
    extern __shared__ unsigned int s_packed[];   // nwords words (~50 KB)
    __shared__ float tab[9][16];
    __shared__ int scnt[NS_MAX];

    for (int w = threadIdx.x; w < nwords; w += P1_TPB)
        s_packed[w] = packed[w];                 // coalesced, L2-resident
    if (threadIdx.x < NS) scnt[threadIdx.x] = 0;

    if (threadIdx.x < 16) {
        const float cc[4] = {0.02817f, 0.28022f, 0.50986f, 0.18175f};
        const float dd[4] = {0.20162f, 0.4029f, 0.94229f, 3.1998f};
        const float COUL = 14.399645478425668f;
        int t = threadIdx.x;
        int ti = t >> 2, tj = t & 3;
        float zi = znum[ti], zj = znum[tj];
        float rc = rcov[ti] + rcov[tj];
        float a = 0.4685f / (powf(zi, 0.23f) + powf(zj, 0.23f));
        float inva = 1.0f / a;
        float factor = COUL * zi * zj;
        float da[4], ee[4];
        float phi = 0.0f, dphi = 0.0f, d2phi = 0.0f;
        #pragma unroll
        for (int k = 0; k < 4; ++k) {
            da[k] = dd[k] * inva;
            ee[k] = expf(-rc * da[k]);
            phi   += cc[k] * ee[k];
            dphi  -= cc[k] * da[k] * ee[k];
            d2phi += cc[k] * da[k] * da[k] * ee[k];
        }
        float invrc = 1.0f / rc;
        float ec   = factor * invrc * phi;
        float dec  = factor * invrc * (-phi * invrc + dphi);
        float d2ec = factor * invrc * (d2phi - 2.0f * invrc * dphi + 2.0f * phi * invrc * invrc);
        float A = (-3.0f * dec + rc * d2ec) * invrc * invrc;
        float B = (2.0f * dec - rc * d2ec) * invrc * invrc * invrc;
        float Cc = -ec + 0.5f * rc * dec - rc * rc * d2ec * (1.0f / 12.0f);
        const float L2E = 1.4426950408889634f;
        tab[0][t] = 0.5f * factor;      // folds final e/2
        tab[1][t] = rc;
        tab[2][t] = -da[0] * L2E;       // c*exp(-r*da) = exp2(r*slope + log2 c)
        tab[3][t] = -da[1] * L2E;
        tab[4][t] = -da[2] * L2E;
        tab[5][t] = -da[3] * L2E;
        tab[6][t] = A * (1.0f / 6.0f);
        tab[7][t] = B * 0.125f;
        tab[8][t] = Cc * 0.5f;
    }
    __syncthreads();

    const float lc0 = -5.1497481f;   // log2(0.02817)
    const float lc1 = -1.8353434f;   // log2(0.28022)
    const float lc2 = -0.9718340f;   // log2(0.50986)
    const float lc3 = -2.4600449f;   // log2(0.18175)

    const float4* rij4 = (const float4*)rij;
    const int4*   fa4  = (const int4*)fa;
    const int4*   sa4  = (const int4*)sa;

    size_t myreg = (size_t)blockIdx.x * NS;

    int q0 = blockIdx.x * chunkQ;
    int q1 = q0 + chunkQ; if (q1 > nquad) q1 = nquad;

    for (int q = q0 + threadIdx.x; q < q1; q += P1_TPB) {
        float4 rv = rij4[q];
        int4   iv = fa4[q];
        int4   jv = sa4[q];
        float ra[4] = {rv.x, rv.y, rv.z, rv.w};
        int   ia[4] = {iv.x, iv.y, iv.z, iv.w};
        int   ja[4] = {jv.x, jv.y, jv.z, jv.w};
        int   ta[4];
        #pragma unroll
        for (int k = 0; k < 4; ++k) {
            int i = ia[k], j = ja[k];
            unsigned int wi = s_packed[i >> 4], wj = s_packed[j >> 4];
            unsigned int ti = (wi >> ((i & 15) * 2)) & 3u;
            unsigned int tj = (wj >> ((j & 15) * 2)) & 3u;
            ta[k] = (int)((ti << 2) | tj);
        }
        #pragma unroll
        for (int k = 0; k < 4; ++k) {
            int t = ta[k];
            float r = ra[k];
            int atom = ia[k];
            bool pass = (r <= tab[1][t]);
            float e = 0.0f;
            if (pass) {
                float p = __builtin_amdgcn_exp2f(__builtin_fmaf(r, tab[2][t], lc0))
                        + __builtin_amdgcn_exp2f(__builtin_fmaf(r, tab[3][t], lc1))
                        + __builtin_amdgcn_exp2f(__builtin_fmaf(r, tab[4][t], lc2))
                        + __builtin_amdgcn_exp2f(__builtin_fmaf(r, tab[5][t], lc3));
                float r3 = r * r * r;
                float poly = __builtin_fmaf(__builtin_fmaf(tab[7][t], r, tab[6][t]), r3, tab[8][t]);
                e = __builtin_fmaf(tab[0][t] * p, __builtin_amdgcn_rcpf(r), poly);
            }
            int sb = atom >> SB_BITS;
            // wave-aggregated slot allocation + contiguous store per super-bucket
            for (int s = 0; s < NS; ++s) {
                bool mine = pass && (sb == s);
                unsigned long long m = __ballot(mine);
                if (m == 0ull) continue;                  // wave-uniform
                int prefix = __builtin_amdgcn_mbcnt_hi((unsigned)(m >> 32),
                             __builtin_amdgcn_mbcnt_lo((unsigned)m, 0));
                int leader = __ffsll((unsigned long long)m) - 1;
                int base0 = 0;
                if (mine && prefix == 0)
                    base0 = atomicAdd(&scnt[s], __popcll(m));  // one LDS atomic/wave
                int base = __shfl(base0, leader);
                if (mine) {
                    int slot = base + prefix;
                    if (slot < cap)
                        regions[(myreg + s) * (size_t)cap + slot] =
                            make_int2(__float_as_int(e), atom);
                    else
                        unsafeAtomicAdd(&fallback[atom], e);   // rare overflow
                }
            }
        }
    }

    // tail (E % 4 != 0): straight to fallback (at most 3 edges)
    if (blockIdx.x == 0) {
        for (int idx = nquad * 4 + threadIdx.x; idx < E; idx += P1_TPB) {
            int i = fa[idx], j = sa[idx];
            unsigned int wi = s_packed[i >> 4], wj = s_packed[j >> 4];
            int t = (int)((((wi >> ((i & 15) * 2)) & 3u) << 2) |
                           ((wj >> ((j & 15) * 2)) & 3u));
            float r = rij[idx];
            if (r <= tab[1][t]) {
                float p = __builtin_amdgcn_exp2f(__builtin_fmaf(r, tab[2][t], lc0))
                        + __builtin_amdgcn_exp2f(__builtin_fmaf(r, tab[3][t], lc1))
                        + __builtin_amdgcn_exp2f(__builtin_fmaf(r, tab[4][t], lc2))
                        + __builtin_amdgcn_exp2f(__builtin_fmaf(r, tab[5][t], lc3));
                float r3 = r * r * r;
                float poly = __builtin_fmaf(__builtin_fmaf(tab[7][t], r, tab[6][t]), r3, tab[8][t]);
                float e = __builtin_fmaf(tab[0][t] * p, __builtin_amdgcn_rcpf(r), poly);
                unsafeAtomicAdd(&fallback[i], e);
            }
        }
    }

    __syncthreads();
    if (cap > 0 && threadIdx.x < NS)
        counts[threadIdx.x * P1_BLOCKS + blockIdx.x] = min(scnt[threadIdx.x], cap);
}

// ------- Phase 2: (super-bucket, replica) -> 64 KB LDS accumulator, NO atomics -------
__global__ __launch_bounds__(P2_TPB) void zbl_agg(
    const int2* __restrict__ regions,
    const int*  __restrict__ counts,     // [NS][P1_BLOCKS]
    float* __restrict__ partials,        // [NS][R_SUB][SBS]
    int NS, int cap)
{
    __shared__ float acc[SBS];
    int s = blockIdx.x;                  // super-bucket
    int r = blockIdx.y;                  // replica
    for (int i = threadIdx.x; i < SBS; i += P2_TPB) acc[i] = 0.0f;
    __syncthreads();

    for (int p = r; p < P1_BLOCKS; p += R_SUB) {
        int n = counts[s * P1_BLOCKS + p];               // uniform load
        size_t base = ((size_t)p * NS + s) * (size_t)cap;
        for (int t = threadIdx.x; t < n; t += P2_TPB) {
            int2 rec = regions[base + t];                // coalesced 8 B
            atomicAdd(&acc[rec.y & (SBS - 1)], __int_as_float(rec.x)); // ds_add_f32
        }
    }
    __syncthreads();

    float* dst = partials + ((size_t)s * R_SUB + r) * SBS;
    for (int i = threadIdx.x; i < SBS; i += P2_TPB)
        dst[i] = acc[i];                                 // plain coalesced stores
}

// ------- Phase 3: reduce R_SUB partials + fallback -> out -------
__global__ __launch_bounds__(TPB_RED) void zbl_red(
    const float* __restrict__ partials,
    const float* __restrict__ fallback,
    float* __restrict__ out,
    int natoms)
{
    int atom = blockIdx.x * TPB_RED + threadIdx.x;
    if (atom >= natoms) return;
    int s = atom >> SB_BITS, i = atom & (SBS - 1);
    float acc = fallback[atom];
    const float* p = partials + (size_t)s * R_SUB * SBS + i;
    for (int k = 0; k < R_SUB; ++k) acc += p[(size_t)k * SBS];
    out[atom] = acc;
}

extern "C" void kernel_launch(void* const* d_in, const int* in_sizes, int n_in,
                              void* d_out, int out_size, void* d_ws, size_t ws_size,
                              hipStream_t stream) {
    const float* rij  = (const float*)d_in[0];
    const float* rcov = (const float*)d_in[1];
    const float* znum = (const float*)d_in[2];
    const int*   fa   = (const int*)d_in[3];
    const int*   sa   = (const int*)d_in[4];
    const int*   types= (const int*)d_in[5];
    float* out = (float*)d_out;
    int E = in_sizes[0];
    int natoms = out_size;
    int nquad = E / 4;
    int nwords = (natoms + 15) / 16;
    int NS = (natoms + SBS - 1) >> SB_BITS;      // 13 for 200K atoms
    if (NS > NS_MAX) NS = NS_MAX;                // (natoms <= 256K)
    int chunkQ = (nquad + P1_BLOCKS - 1) / P1_BLOCKS;

    // ws layout: [packed][counts][fallback][partials][regions...]
    size_t packed_bytes = ((size_t)nwords * 4 + 255) & ~(size_t)255;
    size_t cnt_bytes    = ((size_t)NS * P1_BLOCKS * 4 + 255) & ~(size_t)255;
    size_t fb_bytes     = ((size_t)natoms * 4 + 255) & ~(size_t)255;
    size_t part_bytes   = ((size_t)NS * R_SUB * SBS * 4 + 255) & ~(size_t)255;
    unsigned int* packed = (unsigned int*)d_ws;
    int*   counts   = (int*)  ((char*)d_ws + packed_bytes);
    float* fallback = (float*)((char*)d_ws + packed_bytes + cnt_bytes);
    float* partials = (float*)((char*)d_ws + packed_bytes + cnt_bytes + fb_bytes);
    int2*  regions  = (int2*) ((char*)d_ws + packed_bytes + cnt_bytes
                               + fb_bytes + part_bytes);

    long long avail = (long long)ws_size
                    - (long long)(packed_bytes + cnt_bytes + fb_bytes + part_bytes);
    int cap = 0;
    if (avail > 0) cap = (int)(avail / ((long long)P1_BLOCKS * (long long)NS * 8));
    if (cap > CAP_MAX) cap = CAP_MAX;

    size_t smem = (size_t)nwords * sizeof(unsigned int);

    zbl_pack<<<(nwords + TPB_PACK - 1) / TPB_PACK, TPB_PACK, 0, stream>>>(
        types, packed, natoms, nwords);

    if (cap >= 64) {
        hipMemsetAsync(fallback, 0, fb_bytes, stream);
        zbl_bin<<<P1_BLOCKS, P1_TPB, smem, stream>>>(
            rij, rcov, znum, fa, sa, packed, regions, counts, fallback,
            E, nquad, natoms, nwords, NS, cap, chunkQ);
        dim3 g2(NS, R_SUB);
        zbl_agg<<<g2, P2_TPB, 0, stream>>>(regions, counts, partials, NS, cap);
        zbl_red<<<(natoms + TPB_RED - 1) / TPB_RED, TPB_RED, 0, stream>>>(
            partials, fallback, out, natoms);
    } else {
        // ws too small: everything overflows straight into out (correct, slow)
        hipMemsetAsync(d_out, 0, (size_t)natoms * 4, stream);
        zbl_bin<<<P1_BLOCKS, P1_TPB, smem, stream>>>(
            rij, rcov, znum, fa, sa, packed, regions, counts, out,
            E, nquad, natoms, nwords, NS, 0, chunkQ);
    }
}

// Round 8
// 173.891 us; speedup vs baseline: 1.2676x; 1.2051x over previous
//
#include <hip/hip_runtime.h>

#define TPB_PACK  256
#define P1_BLOCKS 512
#define P1_TPB    512
#define SB_BITS   14
#define SBS       (1 << SB_BITS)     // atoms per super-bucket (16384)
#define NS_MAX    16
#define P2_TPB    1024
#define R_SUB     24                 // phase-2 replicas per super-bucket
#define TPB_RED   256
#define CAP_MAX   1024

// ---- pack atom types (2 bits each) AND zero the fallback accumulator ----
__global__ __launch_bounds__(TPB_PACK) void zbl_pack(
    const int* __restrict__ types, unsigned int* __restrict__ packed,
    float* __restrict__ fallback, int natoms, int nwords)
{
    int tid = blockIdx.x * TPB_PACK + threadIdx.x;
    int nth = gridDim.x * TPB_PACK;
    for (int w = tid; w < nwords; w += nth) {
        int base = w << 4;
        unsigned int word = 0;
        #pragma unroll
        for (int j = 0; j < 16; ++j) {
            int i = base + j;
            unsigned int t = (i < natoms) ? (unsigned int)types[i] : 0u;
            word |= (t & 3u) << (2 * j);
        }
        packed[w] = word;
    }
    for (int i = tid; i < natoms; i += nth) fallback[i] = 0.0f;
}

// ------- Phase 1: LDS type table; per-lane binning into NS coarse buckets -------
// Coarse buckets (16K atoms): ~36 passing lanes spread over 13 counters, so
// lanes sharing a bucket get HW-sequential slots -> contiguous store addresses
// -> ~13 store transactions/wave (R7's coalescing) without R7's ballot VALU.
__global__ __launch_bounds__(P1_TPB) void zbl_bin(
    const float* __restrict__ rij,
    const float* __restrict__ rcov,
    const float* __restrict__ znum,
    const int*  __restrict__ fa,
    const int*  __restrict__ sa,
    const unsigned int* __restrict__ packed,
    int2*  __restrict__ regions,     // [P1_BLOCKS][NS][cap] records {e_bits, atom}
    int*   __restrict__ counts,      // [NS][P1_BLOCKS] (transposed)
    float* __restrict__ fallback,    // natoms floats, pre-zeroed (= d_out if cap==0)
    int E, int nquad, int natoms, int nwords, int NS, int cap, int chunkQ)
{
    extern __shared__ unsigned int s_packed[];   // nwords words (~50 KB)
    __shared__ float tab[9][16];
    __shared__ int scnt[NS_MAX];

    for (int w = threadIdx.x; w < nwords; w += P1_TPB)
        s_packed[w] = packed[w];                 // coalesced, L2-resident
    if (threadIdx.x < NS) scnt[threadIdx.x] = 0;

    if (threadIdx.x < 16) {
        const float cc[4] = {0.02817f, 0.28022f, 0.50986f, 0.18175f};
        const float dd[4] = {0.20162f, 0.4029f, 0.94229f, 3.1998f};
        const float COUL = 14.399645478425668f;
        int t = threadIdx.x;
        int ti = t >> 2, tj = t & 3;
        float zi = znum[ti], zj = znum[tj];
        float rc = rcov[ti] + rcov[tj];
        float a = 0.4685f / (powf(zi, 0.23f) + powf(zj, 0.23f));
        float inva = 1.0f / a;
        float factor = COUL * zi * zj;
        float da[4], ee[4];
        float phi = 0.0f, dphi = 0.0f, d2phi = 0.0f;
        #pragma unroll
        for (int k = 0; k < 4; ++k) {
            da[k] = dd[k] * inva;
            ee[k] = expf(-rc * da[k]);
            phi   += cc[k] * ee[k];
            dphi  -= cc[k] * da[k] * ee[k];
            d2phi += cc[k] * da[k] * da[k] * ee[k];
        }
        float invrc = 1.0f / rc;
        float ec   = factor * invrc * phi;
        float dec  = factor * invrc * (-phi * invrc + dphi);
        float d2ec = factor * invrc * (d2phi - 2.0f * invrc * dphi + 2.0f * phi * invrc * invrc);
        float A = (-3.0f * dec + rc * d2ec) * invrc * invrc;
        float B = (2.0f * dec - rc * d2ec) * invrc * invrc * invrc;
        float Cc = -ec + 0.5f * rc * dec - rc * rc * d2ec * (1.0f / 12.0f);
        const float L2E = 1.4426950408889634f;
        tab[0][t] = 0.5f * factor;      // folds final e/2
        tab[1][t] = rc;
        tab[2][t] = -da[0] * L2E;       // c*exp(-r*da) = exp2(r*slope + log2 c)
        tab[3][t] = -da[1] * L2E;
        tab[4][t] = -da[2] * L2E;
        tab[5][t] = -da[3] * L2E;
        tab[6][t] = A * (1.0f / 6.0f);
        tab[7][t] = B * 0.125f;
        tab[8][t] = Cc * 0.5f;
    }
    __syncthreads();

    const float lc0 = -5.1497481f;   // log2(0.02817)
    const float lc1 = -1.8353434f;   // log2(0.28022)
    const float lc2 = -0.9718340f;   // log2(0.50986)
    const float lc3 = -2.4600449f;   // log2(0.18175)

    const float4* rij4 = (const float4*)rij;
    const int4*   fa4  = (const int4*)fa;
    const int4*   sa4  = (const int4*)sa;

    size_t myreg = (size_t)blockIdx.x * NS;

    int q0 = blockIdx.x * chunkQ;
    int q1 = q0 + chunkQ; if (q1 > nquad) q1 = nquad;

    for (int q = q0 + threadIdx.x; q < q1; q += P1_TPB) {
        float4 rv = rij4[q];
        int4   iv = fa4[q];
        int4   jv = sa4[q];
        float ra[4] = {rv.x, rv.y, rv.z, rv.w};
        int   ia[4] = {iv.x, iv.y, iv.z, iv.w};
        int   ja[4] = {jv.x, jv.y, jv.z, jv.w};
        int   ta[4];
        #pragma unroll
        for (int k = 0; k < 4; ++k) {
            int i = ia[k], j = ja[k];
            unsigned int wi = s_packed[i >> 4], wj = s_packed[j >> 4];
            unsigned int ti = (wi >> ((i & 15) * 2)) & 3u;
            unsigned int tj = (wj >> ((j & 15) * 2)) & 3u;
            ta[k] = (int)((ti << 2) | tj);
        }
        #pragma unroll
        for (int k = 0; k < 4; ++k) {
            int t = ta[k];
            float r = ra[k];
            if (r <= tab[1][t]) {
                float p = __builtin_amdgcn_exp2f(__builtin_fmaf(r, tab[2][t], lc0))
                        + __builtin_amdgcn_exp2f(__builtin_fmaf(r, tab[3][t], lc1))
                        + __builtin_amdgcn_exp2f(__builtin_fmaf(r, tab[4][t], lc2))
                        + __builtin_amdgcn_exp2f(__builtin_fmaf(r, tab[5][t], lc3));
                float r3 = r * r * r;
                float poly = __builtin_fmaf(__builtin_fmaf(tab[7][t], r, tab[6][t]), r3, tab[8][t]);
                float e = __builtin_fmaf(tab[0][t] * p, __builtin_amdgcn_rcpf(r), poly);
                int atom = ia[k];
                int s = atom >> SB_BITS;
                int slot = atomicAdd(&scnt[s], 1);   // LDS atomic; same-bucket lanes
                                                     // get sequential slots
                if (slot < cap)
                    regions[(myreg + s) * (size_t)cap + slot] =
                        make_int2(__float_as_int(e), atom);
                else
                    unsafeAtomicAdd(&fallback[atom], e);   // rare overflow
            }
        }
    }

    // tail (E % 4 != 0): straight to fallback (at most 3 edges)
    if (blockIdx.x == 0) {
        for (int idx = nquad * 4 + threadIdx.x; idx < E; idx += P1_TPB) {
            int i = fa[idx], j = sa[idx];
            unsigned int wi = s_packed[i >> 4], wj = s_packed[j >> 4];
            int t = (int)((((wi >> ((i & 15) * 2)) & 3u) << 2) |
                           ((wj >> ((j & 15) * 2)) & 3u));
            float r = rij[idx];
            if (r <= tab[1][t]) {
                float p = __builtin_amdgcn_exp2f(__builtin_fmaf(r, tab[2][t], lc0))
                        + __builtin_amdgcn_exp2f(__builtin_fmaf(r, tab[3][t], lc1))
                        + __builtin_amdgcn_exp2f(__builtin_fmaf(r, tab[4][t], lc2))
                        + __builtin_amdgcn_exp2f(__builtin_fmaf(r, tab[5][t], lc3));
                float r3 = r * r * r;
                float poly = __builtin_fmaf(__builtin_fmaf(tab[7][t], r, tab[6][t]), r3, tab[8][t]);
                float e = __builtin_fmaf(tab[0][t] * p, __builtin_amdgcn_rcpf(r), poly);
                unsafeAtomicAdd(&fallback[i], e);
            }
        }
    }

    __syncthreads();
    if (cap > 0 && threadIdx.x < NS)
        counts[threadIdx.x * P1_BLOCKS + blockIdx.x] = min(scnt[threadIdx.x], cap);
}

// ------- Phase 2: (super-bucket, replica) -> 64 KB LDS accumulator, NO global atomics -------
__global__ __launch_bounds__(P2_TPB) void zbl_agg(
    const int2* __restrict__ regions,
    const int*  __restrict__ counts,     // [NS][P1_BLOCKS]
    float* __restrict__ partials,        // [NS][R_SUB][SBS]
    int NS, int cap)
{
    __shared__ float acc[SBS];           // 64 KB
    int s = blockIdx.x;                  // super-bucket
    int r = blockIdx.y;                  // replica
    for (int i = threadIdx.x; i < SBS; i += P2_TPB) acc[i] = 0.0f;
    __syncthreads();

    for (int p = r; p < P1_BLOCKS; p += R_SUB) {
        int n = counts[s * P1_BLOCKS + p];               // uniform load
        size_t base = ((size_t)p * NS + s) * (size_t)cap;
        for (int t = threadIdx.x; t < n; t += P2_TPB) {
            int2 rec = regions[base + t];                // coalesced 8 B
            atomicAdd(&acc[rec.y & (SBS - 1)], __int_as_float(rec.x)); // ds_add_f32
        }
    }
    __syncthreads();

    float* dst = partials + ((size_t)s * R_SUB + r) * SBS;
    for (int i = threadIdx.x; i < SBS; i += P2_TPB)
        dst[i] = acc[i];                                 // plain coalesced stores
}

// ------- Phase 3: reduce R_SUB partials + fallback -> out -------
__global__ __launch_bounds__(TPB_RED) void zbl_red(
    const float* __restrict__ partials,
    const float* __restrict__ fallback,
    float* __restrict__ out,
    int natoms)
{
    int atom = blockIdx.x * TPB_RED + threadIdx.x;
    if (atom >= natoms) return;
    int s = atom >> SB_BITS, i = atom & (SBS - 1);
    float acc = fallback[atom];
    const float* p = partials + (size_t)s * R_SUB * SBS + i;
    #pragma unroll
    for (int k = 0; k < R_SUB; ++k) acc += p[(size_t)k * SBS];
    out[atom] = acc;
}

extern "C" void kernel_launch(void* const* d_in, const int* in_sizes, int n_in,
                              void* d_out, int out_size, void* d_ws, size_t ws_size,
                              hipStream_t stream) {
    const float* rij  = (const float*)d_in[0];
    const float* rcov = (const float*)d_in[1];
    const float* znum = (const float*)d_in[2];
    const int*   fa   = (const int*)d_in[3];
    const int*   sa   = (const int*)d_in[4];
    const int*   types= (const int*)d_in[5];
    float* out = (float*)d_out;
    int E = in_sizes[0];
    int natoms = out_size;
    int nquad = E / 4;
    int nwords = (natoms + 15) / 16;
    int NS = (natoms + SBS - 1) >> SB_BITS;      // 13 for 200K atoms
    if (NS > NS_MAX) NS = NS_MAX;                // (natoms <= 256K)
    int chunkQ = (nquad + P1_BLOCKS - 1) / P1_BLOCKS;

    // ws layout: [packed][counts][fallback][partials][regions...]
    size_t packed_bytes = ((size_t)nwords * 4 + 255) & ~(size_t)255;
    size_t cnt_bytes    = ((size_t)NS * P1_BLOCKS * 4 + 255) & ~(size_t)255;
    size_t fb_bytes     = ((size_t)natoms * 4 + 255) & ~(size_t)255;
    size_t part_bytes   = ((size_t)NS * R_SUB * SBS * 4 + 255) & ~(size_t)255;
    unsigned int* packed = (unsigned int*)d_ws;
    int*   counts   = (int*)  ((char*)d_ws + packed_bytes);
    float* fallback = (float*)((char*)d_ws + packed_bytes + cnt_bytes);
    float* partials = (float*)((char*)d_ws + packed_bytes + cnt_bytes + fb_bytes);
    int2*  regions  = (int2*) ((char*)d_ws + packed_bytes + cnt_bytes
                               + fb_bytes + part_bytes);

    long long avail = (long long)ws_size
                    - (long long)(packed_bytes + cnt_bytes + fb_bytes + part_bytes);
    int cap = 0;
    if (avail > 0) cap = (int)(avail / ((long long)P1_BLOCKS * (long long)NS * 8));
    if (cap > CAP_MAX) cap = CAP_MAX;

    size_t smem = (size_t)nwords * sizeof(unsigned int);

    if (cap >= 64) {
        zbl_pack<<<96, TPB_PACK, 0, stream>>>(types, packed, fallback, natoms, nwords);
        zbl_bin<<<P1_BLOCKS, P1_TPB, smem, stream>>>(
            rij, rcov, znum, fa, sa, packed, regions, counts, fallback,
            E, nquad, natoms, nwords, NS, cap, chunkQ);
        dim3 g2(NS, R_SUB);
        zbl_agg<<<g2, P2_TPB, 0, stream>>>(regions, counts, partials, NS, cap);
        zbl_red<<<(natoms + TPB_RED - 1) / TPB_RED, TPB_RED, 0, stream>>>(
            partials, fallback, out, natoms);
    } else {
        // ws too small: everything overflows straight into out (correct, slow)
        zbl_pack<<<96, TPB_PACK, 0, stream>>>(types, packed, out, natoms, nwords);
        zbl_bin<<<P1_BLOCKS, P1_TPB, smem, stream>>>(
            rij, rcov, znum, fa, sa, packed, regions, counts, out,
            E, nquad, natoms, nwords, NS, 0, chunkQ);
    }
}

// Round 9
// 172.531 us; speedup vs baseline: 1.2776x; 1.0079x over previous
//
#include <hip/hip_runtime.h>

#define TPB_PACK  256
#define P1_BLOCKS 512
#define P1_TPB    1024
#define SB_BITS   14
#define SBS       (1 << SB_BITS)     // atoms per super-bucket (16384)
#define NS_MAX    16
#define P2_TPB    1024
#define R_SUB     24                 // phase-2 replicas per super-bucket
#define TPB_RED   256
#define CAP_MAX   1024

// ---- pack atom types (2 bits each) AND zero the fallback accumulator ----
__global__ __launch_bounds__(TPB_PACK) void zbl_pack(
    const int* __restrict__ types, unsigned int* __restrict__ packed,
    float* __restrict__ fallback, int natoms, int nwords)
{
    int tid = blockIdx.x * TPB_PACK + threadIdx.x;
    int nth = gridDim.x * TPB_PACK;
    for (int w = tid; w < nwords; w += nth) {
        int base = w << 4;
        unsigned int word = 0;
        #pragma unroll
        for (int j = 0; j < 16; ++j) {
            int i = base + j;
            unsigned int t = (i < natoms) ? (unsigned int)types[i] : 0u;
            word |= (t & 3u) << (2 * j);
        }
        packed[w] = word;
    }
    for (int i = tid; i < natoms; i += nth) fallback[i] = 0.0f;
}

// ------- Phase 1: LDS type table; per-lane binning into NS coarse buckets -------
// Coarse buckets (16K atoms): same-bucket lanes get HW-sequential slots from one
// LDS atomic -> contiguous store addresses -> ~NS store txns/wave.
// Table packed as float4 pairs: 3 ds instrs per passing edge instead of 9.
__global__ __launch_bounds__(P1_TPB) void zbl_bin(
    const float* __restrict__ rij,
    const float* __restrict__ rcov,
    const float* __restrict__ znum,
    const int*  __restrict__ fa,
    const int*  __restrict__ sa,
    const unsigned int* __restrict__ packed,
    int2*  __restrict__ regions,     // [P1_BLOCKS][NS][cap] records {e_bits, atom}
    int*   __restrict__ counts,      // [NS][P1_BLOCKS] (transposed)
    float* __restrict__ fallback,    // natoms floats, pre-zeroed (= d_out if cap==0)
    int E, int nquad, int natoms, int nwords, int NS, int cap, int chunkQ)
{
    extern __shared__ unsigned int s_packed[];   // nwords words (~50 KB)
    __shared__ float4 tabB[16];                  // {rc, factor/2, A/6, B/8}
    __shared__ float4 tabA[16];                  // exp2 slopes for the 4 terms
    __shared__ float  tabC[16];                  // C/2
    __shared__ int scnt[NS_MAX];

    for (int w = threadIdx.x; w < nwords; w += P1_TPB)
        s_packed[w] = packed[w];                 // coalesced, L2-resident
    if (threadIdx.x < NS) scnt[threadIdx.x] = 0;

    if (threadIdx.x < 16) {
        const float cc[4] = {0.02817f, 0.28022f, 0.50986f, 0.18175f};
        const float dd[4] = {0.20162f, 0.4029f, 0.94229f, 3.1998f};
        const float COUL = 14.399645478425668f;
        int t = threadIdx.x;
        int ti = t >> 2, tj = t & 3;
        float zi = znum[ti], zj = znum[tj];
        float rc = rcov[ti] + rcov[tj];
        float a = 0.4685f / (powf(zi, 0.23f) + powf(zj, 0.23f));
        float inva = 1.0f / a;
        float factor = COUL * zi * zj;
        float da[4], ee[4];
        float phi = 0.0f, dphi = 0.0f, d2phi = 0.0f;
        #pragma unroll
        for (int k = 0; k < 4; ++k) {
            da[k] = dd[k] * inva;
            ee[k] = expf(-rc * da[k]);
            phi   += cc[k] * ee[k];
            dphi  -= cc[k] * da[k] * ee[k];
            d2phi += cc[k] * da[k] * da[k] * ee[k];
        }
        float invrc = 1.0f / rc;
        float ec   = factor * invrc * phi;
        float dec  = factor * invrc * (-phi * invrc + dphi);
        float d2ec = factor * invrc * (d2phi - 2.0f * invrc * dphi + 2.0f * phi * invrc * invrc);
        float A = (-3.0f * dec + rc * d2ec) * invrc * invrc;
        float B = (2.0f * dec - rc * d2ec) * invrc * invrc * invrc;
        float Cc = -ec + 0.5f * rc * dec - rc * rc * d2ec * (1.0f / 12.0f);
        const float L2E = 1.4426950408889634f;
        tabB[t] = make_float4(rc, 0.5f * factor, A * (1.0f / 6.0f), B * 0.125f);
        tabA[t] = make_float4(-da[0] * L2E, -da[1] * L2E, -da[2] * L2E, -da[3] * L2E);
        tabC[t] = Cc * 0.5f;
    }
    __syncthreads();

    const float lc0 = -5.1497481f;   // log2(0.02817)
    const float lc1 = -1.8353434f;   // log2(0.28022)
    const float lc2 = -0.9718340f;   // log2(0.50986)
    const float lc3 = -2.4600449f;   // log2(0.18175)

    const float4* rij4 = (const float4*)rij;
    const int4*   fa4  = (const int4*)fa;
    const int4*   sa4  = (const int4*)sa;

    size_t myreg = (size_t)blockIdx.x * NS;

    int q0 = blockIdx.x * chunkQ;
    int q1 = q0 + chunkQ; if (q1 > nquad) q1 = nquad;

    for (int q = q0 + threadIdx.x; q < q1; q += P1_TPB) {
        float4 rv = rij4[q];
        int4   iv = fa4[q];
        int4   jv = sa4[q];
        float ra[4] = {rv.x, rv.y, rv.z, rv.w};
        int   ia[4] = {iv.x, iv.y, iv.z, iv.w};
        int   ja[4] = {jv.x, jv.y, jv.z, jv.w};
        int   ta[4];
        #pragma unroll
        for (int k = 0; k < 4; ++k) {
            int i = ia[k], j = ja[k];
            unsigned int wi = s_packed[i >> 4], wj = s_packed[j >> 4];
            unsigned int ti = (wi >> ((i & 15) * 2)) & 3u;
            unsigned int tj = (wj >> ((j & 15) * 2)) & 3u;
            ta[k] = (int)((ti << 2) | tj);
        }
        float eo[4];
        bool  po[4];
        #pragma unroll
        for (int k = 0; k < 4; ++k) {
            int t = ta[k];
            float r = ra[k];
            float4 B = tabB[t];                 // one ds_read_b128: rc,f/2,A/6,B/8
            bool pass = (r <= B.x);
            po[k] = pass;
            float e = 0.0f;
            if (pass) {
                float4 S = tabA[t];             // ds_read_b128: slopes
                float c2 = tabC[t];             // ds_read_b32
                float p = __builtin_amdgcn_exp2f(__builtin_fmaf(r, S.x, lc0))
                        + __builtin_amdgcn_exp2f(__builtin_fmaf(r, S.y, lc1))
                        + __builtin_amdgcn_exp2f(__builtin_fmaf(r, S.z, lc2))
                        + __builtin_amdgcn_exp2f(__builtin_fmaf(r, S.w, lc3));
                float r3 = r * r * r;
                float poly = __builtin_fmaf(__builtin_fmaf(B.w, r, B.z), r3, c2);
                e = __builtin_fmaf(B.y * p, __builtin_amdgcn_rcpf(r), poly);
            }
            eo[k] = e;
        }
        // second phase: slot allocation + stores back-to-back
        #pragma unroll
        for (int k = 0; k < 4; ++k) {
            if (po[k]) {
                int atom = ia[k];
                int s = atom >> SB_BITS;
                int slot = atomicAdd(&scnt[s], 1);   // same-bucket lanes -> sequential slots
                if (slot < cap)
                    regions[(myreg + s) * (size_t)cap + slot] =
                        make_int2(__float_as_int(eo[k]), atom);
                else
                    unsafeAtomicAdd(&fallback[atom], eo[k]);   // rare overflow
            }
        }
    }

    // tail (E % 4 != 0): straight to fallback (at most 3 edges)
    if (blockIdx.x == 0) {
        for (int idx = nquad * 4 + threadIdx.x; idx < E; idx += P1_TPB) {
            int i = fa[idx], j = sa[idx];
            unsigned int wi = s_packed[i >> 4], wj = s_packed[j >> 4];
            int t = (int)((((wi >> ((i & 15) * 2)) & 3u) << 2) |
                           ((wj >> ((j & 15) * 2)) & 3u));
            float r = rij[idx];
            float4 B = tabB[t];
            if (r <= B.x) {
                float4 S = tabA[t];
                float c2 = tabC[t];
                float p = __builtin_amdgcn_exp2f(__builtin_fmaf(r, S.x, lc0))
                        + __builtin_amdgcn_exp2f(__builtin_fmaf(r, S.y, lc1))
                        + __builtin_amdgcn_exp2f(__builtin_fmaf(r, S.z, lc2))
                        + __builtin_amdgcn_exp2f(__builtin_fmaf(r, S.w, lc3));
                float r3 = r * r * r;
                float poly = __builtin_fmaf(__builtin_fmaf(B.w, r, B.z), r3, c2);
                float e = __builtin_fmaf(B.y * p, __builtin_amdgcn_rcpf(r), poly);
                unsafeAtomicAdd(&fallback[i], e);
            }
        }
    }

    __syncthreads();
    if (cap > 0 && threadIdx.x < NS)
        counts[threadIdx.x * P1_BLOCKS + blockIdx.x] = min(scnt[threadIdx.x], cap);
}

// ------- Phase 2: (super-bucket, replica) -> 64 KB LDS accumulator, NO global atomics -------
__global__ __launch_bounds__(P2_TPB) void zbl_agg(
    const int2* __restrict__ regions,
    const int*  __restrict__ counts,     // [NS][P1_BLOCKS]
    float* __restrict__ partials,        // [NS][R_SUB][SBS]
    int NS, int cap)
{
    __shared__ float acc[SBS];           // 64 KB
    int s = blockIdx.x;                  // super-bucket
    int r = blockIdx.y;                  // replica
    for (int i = threadIdx.x; i < SBS; i += P2_TPB) acc[i] = 0.0f;
    __syncthreads();

    for (int p = r; p < P1_BLOCKS; p += R_SUB) {
        int n = counts[s * P1_BLOCKS + p];               // uniform load
        size_t base = ((size_t)p * NS + s) * (size_t)cap;
        for (int t = threadIdx.x; t < n; t += P2_TPB) {
            int2 rec = regions[base + t];                // coalesced 8 B
            atomicAdd(&acc[rec.y & (SBS - 1)], __int_as_float(rec.x)); // ds_add_f32
        }
    }
    __syncthreads();

    float* dst = partials + ((size_t)s * R_SUB + r) * SBS;
    for (int i = threadIdx.x; i < SBS; i += P2_TPB)
        dst[i] = acc[i];                                 // plain coalesced stores
}

// ------- Phase 3: reduce R_SUB partials + fallback -> out -------
__global__ __launch_bounds__(TPB_RED) void zbl_red(
    const float* __restrict__ partials,
    const float* __restrict__ fallback,
    float* __restrict__ out,
    int natoms)
{
    int atom = blockIdx.x * TPB_RED + threadIdx.x;
    if (atom >= natoms) return;
    int s = atom >> SB_BITS, i = atom & (SBS - 1);
    float acc = fallback[atom];
    const float* p = partials + (size_t)s * R_SUB * SBS + i;
    #pragma unroll
    for (int k = 0; k < R_SUB; ++k) acc += p[(size_t)k * SBS];
    out[atom] = acc;
}

extern "C" void kernel_launch(void* const* d_in, const int* in_sizes, int n_in,
                              void* d_out, int out_size, void* d_ws, size_t ws_size,
                              hipStream_t stream) {
    const float* rij  = (const float*)d_in[0];
    const float* rcov = (const float*)d_in[1];
    const float* znum = (const float*)d_in[2];
    const int*   fa   = (const int*)d_in[3];
    const int*   sa   = (const int*)d_in[4];
    const int*   types= (const int*)d_in[5];
    float* out = (float*)d_out;
    int E = in_sizes[0];
    int natoms = out_size;
    int nquad = E / 4;
    int nwords = (natoms + 15) / 16;
    int NS = (natoms + SBS - 1) >> SB_BITS;      // 13 for 200K atoms
    if (NS > NS_MAX) NS = NS_MAX;                // (natoms <= 256K)
    int chunkQ = (nquad + P1_BLOCKS - 1) / P1_BLOCKS;

    // ws layout: [packed][counts][fallback][partials][regions...]
    size_t packed_bytes = ((size_t)nwords * 4 + 255) & ~(size_t)255;
    size_t cnt_bytes    = ((size_t)NS * P1_BLOCKS * 4 + 255) & ~(size_t)255;
    size_t fb_bytes     = ((size_t)natoms * 4 + 255) & ~(size_t)255;
    size_t part_bytes   = ((size_t)NS * R_SUB * SBS * 4 + 255) & ~(size_t)255;
    unsigned int* packed = (unsigned int*)d_ws;
    int*   counts   = (int*)  ((char*)d_ws + packed_bytes);
    float* fallback = (float*)((char*)d_ws + packed_bytes + cnt_bytes);
    float* partials = (float*)((char*)d_ws + packed_bytes + cnt_bytes + fb_bytes);
    int2*  regions  = (int2*) ((char*)d_ws + packed_bytes + cnt_bytes
                               + fb_bytes + part_bytes);

    long long avail = (long long)ws_size
                    - (long long)(packed_bytes + cnt_bytes + fb_bytes + part_bytes);
    int cap = 0;
    if (avail > 0) cap = (int)(avail / ((long long)P1_BLOCKS * (long long)NS * 8));
    if (cap > CAP_MAX) cap = CAP_MAX;

    size_t smem = (size_t)nwords * sizeof(unsigned int);

    if (cap >= 64) {
        zbl_pack<<<96, TPB_PACK, 0, stream>>>(types, packed, fallback, natoms, nwords);
        zbl_bin<<<P1_BLOCKS, P1_TPB, smem, stream>>>(
            rij, rcov, znum, fa, sa, packed, regions, counts, fallback,
            E, nquad, natoms, nwords, NS, cap, chunkQ);
        dim3 g2(NS, R_SUB);
        zbl_agg<<<g2, P2_TPB, 0, stream>>>(regions, counts, partials, NS, cap);
        zbl_red<<<(natoms + TPB_RED - 1) / TPB_RED, TPB_RED, 0, stream>>>(
            partials, fallback, out, natoms);
    } else {
        // ws too small: everything overflows straight into out (correct, slow)
        zbl_pack<<<96, TPB_PACK, 0, stream>>>(types, packed, out, natoms, nwords);
        zbl_bin<<<P1_BLOCKS, P1_TPB, smem, stream>>>(
            rij, rcov, znum, fa, sa, packed, regions, counts, out,
            E, nquad, natoms, nwords, NS, 0, chunkQ);
    }
}